// Round 2
// baseline (718.211 us; speedup 1.0000x reference)
//
#include <hip/hip_runtime.h>
#include <cstdint>
#include <cstddef>

typedef float f32x4 __attribute__((ext_vector_type(4)));
typedef __bf16 bf16x8 __attribute__((ext_vector_type(8)));
typedef unsigned short u16;

#define Hdim 128
#define DEdim 16
#define APITCH 296   // 592 B row: 16B aligned, 148 words %32 = 20 -> conflict-free b128
#define FOFF   136   // Fb (edge_in, 160 cols) overlays Ab cols [136..296): mes_in tail dead after B2
#define NPITCH 264   // 528 B row: 16B aligned, 132 words %32 = 4 -> 2-way (free)

__device__ __forceinline__ u16 f2bf(float f){
  uint32_t u = __builtin_bit_cast(uint32_t, f);
  u += 0x7fffu + ((u >> 16) & 1u);
  return (u16)(u >> 16);
}
__device__ __forceinline__ uint32_t pack_bf2(float a, float b){
  return (uint32_t)f2bf(a) | ((uint32_t)f2bf(b) << 16);
}
__device__ __forceinline__ float bf2f(uint32_t lo16){
  return __builtin_bit_cast(float, lo16 << 16);
}
__device__ __forceinline__ float silu_f(float x){
  return x / (1.0f + __expf(-x));
}

// C[64 rows][this wave's 32 cols] = A(LDS,bf16) @ Bt(global,bf16)^T + bias
// A-frag: A[rt*16 + (lane&15)][k],  k = kc*32 + (lane>>4)*8 + slot
// B-frag: B[k][ct*16 + (lane&15)]  (same k mapping -> mapping cancels)
// C/D (HW-verified): col = lane&15, row(reg i) = (lane>>4)*4 + i
template<int KC>
__device__ __forceinline__ void gemm_tile(
    const u16* A, int apitch,
    const u16* __restrict__ Bt, int kpad,
    const float* __restrict__ bias,
    int wv, int cidx, int hi, f32x4 (&acc)[4][2])
{
  const int c0 = (wv*2+0)*16 + cidx;
  const int c1 = (wv*2+1)*16 + cidx;
  const float b0 = bias[c0];
  const float b1 = bias[c1];
  #pragma unroll
  for (int rt=0; rt<4; ++rt){
    acc[rt][0] = (f32x4){b0,b0,b0,b0};
    acc[rt][1] = (f32x4){b1,b1,b1,b1};
  }
  #pragma unroll
  for (int kc=0; kc<KC; ++kc){
    const int ko = kc*32 + hi*8;
    bf16x8 bb0 = *(const bf16x8*)(Bt + (size_t)c0*kpad + ko);
    bf16x8 bb1 = *(const bf16x8*)(Bt + (size_t)c1*kpad + ko);
    #pragma unroll
    for (int rt=0; rt<4; ++rt){
      bf16x8 a = *(const bf16x8*)(A + (rt*16+cidx)*apitch + ko);
      acc[rt][0] = __builtin_amdgcn_mfma_f32_16x16x32_bf16(a, bb0, acc[rt][0], 0,0,0);
      acc[rt][1] = __builtin_amdgcn_mfma_f32_16x16x32_bf16(a, bb1, acc[rt][1], 0,0,0);
    }
  }
}

template<bool GATHER>
__global__ __launch_bounds__(256, 4) void egcl_edge(
    const float* __restrict__ h, const float* __restrict__ coord,
    const int* __restrict__ ei, const float* __restrict__ ea,
    const float* __restrict__ mes_b1, const float* __restrict__ mes_b2,
    const float* __restrict__ edge_b1, const float* __restrict__ edge_b2,
    const float* __restrict__ coord_b1, const float* __restrict__ coord_w2,
    const u16* __restrict__ w_mes1t, const u16* __restrict__ w_mes2t,
    const u16* __restrict__ w_coord1t, const u16* __restrict__ w_edge1t,
    const u16* __restrict__ w_edge2t,
    float* __restrict__ agg, u16* __restrict__ feat,
    float* __restrict__ out_coord, float* __restrict__ out_edge, int E, int N)
{
  __shared__ u16 Ab[64*APITCH];   // mes_in(288) -> A2/A6 in [0,128), Fb=edge_in at [136,296)
  __shared__ float cds[64*4];     // coord_diff xyz, radial
  __shared__ float tvs[64];       // coord-MLP scalar per edge
  __shared__ int cnode[64];

  const int tid  = threadIdx.x;
  const int lane = tid & 63;
  const int wv   = tid >> 6;
  const int e0   = blockIdx.x * 64;
  const int cidx = lane & 15;
  const int hi   = lane >> 4;

  // ---------- stage: each wave stages its 16 edges ----------
  {
    const int le   = wv*16 + (lane>>2);
    const int part = lane & 3;
    int eg = e0 + le;
    if (eg >= E) eg = E-1;
    const int node = (part < 2) ? ei[eg] : ei[E + eg];   // 0,1: h[row]; 2,3: h[col]
    const float* src = h + (size_t)node*Hdim + (part&1)*64;
    u16* dst = Ab + le*APITCH + part*64;
    #pragma unroll
    for (int j=0;j<16;++j){
      const float4 v = ((const float4*)src)[j];
      ushort4 o; o.x=f2bf(v.x); o.y=f2bf(v.y); o.z=f2bf(v.z); o.w=f2bf(v.w);
      *(ushort4*)(dst + j*4) = o;
    }
    if (part == 0){
      const int cn = ei[E + eg];
      const float dx = coord[(size_t)node*3+0] - coord[(size_t)cn*3+0];
      const float dy = coord[(size_t)node*3+1] - coord[(size_t)cn*3+1];
      const float dz = coord[(size_t)node*3+2] - coord[(size_t)cn*3+2];
      const float radial = dx*dx + dy*dy + dz*dz;
      const float inv = 1.0f/(sqrtf(radial + 1e-8f) + 1.0f);
      cds[le*4+0]=dx*inv; cds[le*4+1]=dy*inv; cds[le*4+2]=dz*inv; cds[le*4+3]=radial;
      cnode[le] = cn;
      Ab[le*APITCH + 256] = f2bf(radial);
      #pragma unroll
      for (int j=0;j<DEdim;++j)
        Ab[le*APITCH + 257 + j] = f2bf(ea[(size_t)eg*DEdim + j]);
      #pragma unroll
      for (int j=273;j<288;++j) Ab[le*APITCH + j] = 0;
    }
    if (tid < 64) tvs[tid] = 0.f;
  }
  __syncthreads();                                   // B1

  f32x4 acc[4][2];

  // ---------- mes layer 1 (K=273 padded 288) ----------
  gemm_tile<9>(Ab, APITCH, w_mes1t, 288, mes_b1, wv, cidx, hi, acc);
  __syncthreads();                                   // B2: mes_in fully consumed
  #pragma unroll
  for (int rt=0; rt<4; ++rt)
    #pragma unroll
    for (int j=0;j<2;++j){
      const int col = (wv*2+j)*16 + cidx;
      #pragma unroll
      for (int i=0;i<4;++i)
        Ab[(rt*16 + hi*4 + i)*APITCH + col] = f2bf(silu_f(acc[rt][j][i]));
    }
  // edge_in tail: radial at Fb col 128 (Ab 264), ea at Fb 129..144 (Ab 265..280), pad to 160
  if (tid < 64){
    const int row = tid;
    int eg = e0 + row; if (eg >= E) eg = E-1;
    Ab[row*APITCH + FOFF + 128] = f2bf(cds[row*4+3]);
    const float4* eap = (const float4*)(ea + (size_t)eg*DEdim);
    #pragma unroll
    for (int j=0;j<4;++j){
      const float4 v = eap[j];
      Ab[row*APITCH + FOFF + 129 + j*4 + 0] = f2bf(v.x);
      Ab[row*APITCH + FOFF + 129 + j*4 + 1] = f2bf(v.y);
      Ab[row*APITCH + FOFF + 129 + j*4 + 2] = f2bf(v.z);
      Ab[row*APITCH + FOFF + 129 + j*4 + 3] = f2bf(v.w);
    }
    #pragma unroll
    for (int j=145;j<160;++j) Ab[row*APITCH + FOFF + j] = 0;
  }
  __syncthreads();                                   // B3

  // ---------- mes layer 2 -> edge_feat ----------
  gemm_tile<4>(Ab, APITCH, w_mes2t, 128, mes_b2, wv, cidx, hi, acc);
  #pragma unroll
  for (int rt=0; rt<4; ++rt)
    #pragma unroll
    for (int j=0;j<2;++j){
      const int col = (wv*2+j)*16 + cidx;
      #pragma unroll
      for (int i=0;i<4;++i){
        const int row = rt*16 + hi*4 + i;
        const float v = silu_f(acc[rt][j][i]);
        if (!GATHER && e0 + row < E)
          atomicAdd(agg + (size_t)cnode[row]*Hdim + col, v);
        Ab[row*APITCH + FOFF + col] = f2bf(v);
      }
    }
  __syncthreads();                                   // B4

  if (GATHER){
    // stream edge_feat (bf16) to ws, fully coalesced 16B stores
    const int row = tid >> 2, seg = tid & 3;
    if (e0 + row < E){
      const int4* s = (const int4*)(Ab + row*APITCH + FOFF + seg*32);
      int4* d = (int4*)(feat + (size_t)(e0+row)*Hdim + seg*32);
      d[0]=s[0]; d[1]=s[1]; d[2]=s[2]; d[3]=s[3];
    }
  }

  // ---------- coord layer 1 + GEMV with coord_w2 ----------
  gemm_tile<4>(Ab + FOFF, APITCH, w_coord1t, 128, coord_b1, wv, cidx, hi, acc);
  {
    const float cw0 = coord_w2[(wv*2+0)*16 + cidx];
    const float cw1 = coord_w2[(wv*2+1)*16 + cidx];
    #pragma unroll
    for (int rt=0; rt<4; ++rt)
      #pragma unroll
      for (int i=0;i<4;++i){
        float p = silu_f(acc[rt][0][i])*cw0 + silu_f(acc[rt][1][i])*cw1;
        p += __shfl_xor(p, 1);
        p += __shfl_xor(p, 2);
        p += __shfl_xor(p, 4);
        p += __shfl_xor(p, 8);
        if (cidx == 0) atomicAdd(&tvs[rt*16 + hi*4 + i], p);
      }
  }
  __syncthreads();                                   // B5
  if (tid < 192){
    const int le = tid/3, d = tid%3;
    if (e0 + le < E)
      atomicAdd(out_coord + (size_t)cnode[le]*3 + d, cds[le*4+d]*tvs[le]);
  }

  // ---------- edge layer 1 (K=145 padded 160) ----------
  gemm_tile<5>(Ab + FOFF, APITCH, w_edge1t, 160, edge_b1, wv, cidx, hi, acc);
  #pragma unroll
  for (int rt=0; rt<4; ++rt)
    #pragma unroll
    for (int j=0;j<2;++j){
      const int col = (wv*2+j)*16 + cidx;
      #pragma unroll
      for (int i=0;i<4;++i)
        Ab[(rt*16 + hi*4 + i)*APITCH + col] = f2bf(silu_f(acc[rt][j][i]));
    }
  __syncthreads();                                   // B6

  // ---------- edge layer 2 (no activation) ----------
  gemm_tile<4>(Ab, APITCH, w_edge2t, 128, edge_b2, wv, cidx, hi, acc);
  #pragma unroll
  for (int rt=0; rt<4; ++rt)
    #pragma unroll
    for (int j=0;j<2;++j){
      const int col = (wv*2+j)*16 + cidx;
      #pragma unroll
      for (int i=0;i<4;++i){
        const int row = rt*16 + hi*4 + i;
        const int eg = e0 + row;
        if (eg < E) out_edge[(size_t)eg*Hdim + col] = acc[rt][j][i];
      }
    }
}

template<bool GATHER>
__global__ __launch_bounds__(256, 4) void egcl_node(
    const float* __restrict__ h, const float* __restrict__ agg,
    const int* __restrict__ offs, const int* __restrict__ deg,
    const int* __restrict__ elist, const u16* __restrict__ feat,
    const float* __restrict__ node_b1, const float* __restrict__ node_b2,
    const u16* __restrict__ w_node1t, const u16* __restrict__ w_node2t,
    float* __restrict__ out_h, int N)
{
  __shared__ u16 Ab[64*NPITCH];
  const int tid  = threadIdx.x;
  const int lane = tid & 63;
  const int wv   = tid >> 6;
  const int r0   = blockIdx.x * 64;
  const int cidx = lane & 15;
  const int hi   = lane >> 4;

  // stage h into cols [0,128)
  {
    const int le   = wv*16 + (lane>>2);
    const int part = lane & 3;
    int g = r0 + le;
    if (g >= N) g = N-1;
    const float* src = h + (size_t)g*Hdim + part*32;
    u16* dst = Ab + le*NPITCH + part*32;
    #pragma unroll
    for (int j=0;j<8;++j){
      const float4 v = ((const float4*)src)[j];
      ushort4 o; o.x=f2bf(v.x); o.y=f2bf(v.y); o.z=f2bf(v.z); o.w=f2bf(v.w);
      *(ushort4*)(dst + j*4) = o;
    }
  }
  // agg into cols [128,256): gather incoming edge_feat rows, f32 accumulate
  if (GATHER){
    const uint32_t* fp = (const uint32_t*)feat;
    for (int ln=0; ln<16; ++ln){
      const int le = wv*16 + ln;
      const int g = r0 + le;
      float a0 = 0.f, a1 = 0.f;
      if (g < N){
        const int start = __builtin_amdgcn_readfirstlane(offs[g]);
        const int dg    = __builtin_amdgcn_readfirstlane(deg[g]);
        int d = 0;
        for (; d + 4 <= dg; d += 4){
          const int e0 = elist[start+d+0];
          const int e1 = elist[start+d+1];
          const int e2 = elist[start+d+2];
          const int e3 = elist[start+d+3];
          const uint32_t v0 = fp[(size_t)e0*64 + lane];
          const uint32_t v1 = fp[(size_t)e1*64 + lane];
          const uint32_t v2 = fp[(size_t)e2*64 + lane];
          const uint32_t v3 = fp[(size_t)e3*64 + lane];
          a0 += bf2f(v0 & 0xffffu) + bf2f(v1 & 0xffffu) + bf2f(v2 & 0xffffu) + bf2f(v3 & 0xffffu);
          a1 += bf2f(v0 >> 16)     + bf2f(v1 >> 16)     + bf2f(v2 >> 16)     + bf2f(v3 >> 16);
        }
        for (; d < dg; ++d){
          const int e = elist[start+d];
          const uint32_t v = fp[(size_t)e*64 + lane];
          a0 += bf2f(v & 0xffffu);
          a1 += bf2f(v >> 16);
        }
      }
      *(uint32_t*)&Ab[(size_t)le*NPITCH + 128 + lane*2] = pack_bf2(a0, a1);
    }
  } else {
    const int le   = wv*16 + (lane>>2);
    const int part = lane & 3;
    int g = r0 + le;
    if (g >= N) g = N-1;
    const float* src = agg + (size_t)g*Hdim + part*32;
    u16* dst = Ab + le*NPITCH + 128 + part*32;
    #pragma unroll
    for (int j=0;j<8;++j){
      const float4 v = ((const float4*)src)[j];
      ushort4 o; o.x=f2bf(v.x); o.y=f2bf(v.y); o.z=f2bf(v.z); o.w=f2bf(v.w);
      *(ushort4*)(dst + j*4) = o;
    }
  }
  __syncthreads();

  f32x4 acc[4][2];
  gemm_tile<8>(Ab, NPITCH, w_node1t, 256, node_b1, wv, cidx, hi, acc);
  __syncthreads();
  #pragma unroll
  for (int rt=0; rt<4; ++rt)
    #pragma unroll
    for (int j=0;j<2;++j){
      const int col = (wv*2+j)*16 + cidx;
      #pragma unroll
      for (int i=0;i<4;++i)
        Ab[(rt*16 + hi*4 + i)*NPITCH + col] = f2bf(silu_f(acc[rt][j][i]));
    }
  __syncthreads();
  gemm_tile<4>(Ab, NPITCH, w_node2t, 128, node_b2, wv, cidx, hi, acc);
  #pragma unroll
  for (int rt=0; rt<4; ++rt)
    #pragma unroll
    for (int j=0;j<2;++j){
      const int col = (wv*2+j)*16 + cidx;
      #pragma unroll
      for (int i=0;i<4;++i){
        const int row = rt*16 + hi*4 + i;
        const int g = r0 + row;
        if (g < N)
          out_h[(size_t)g*Hdim + col] = h[(size_t)g*Hdim + col] + acc[rt][j][i];
      }
    }
}

__global__ void egcl_init(const float* __restrict__ coord, float* __restrict__ out_coord,
                          int nc, float* __restrict__ zf, int nzf,
                          int* __restrict__ zi, int nzi)
{
  const int i = blockIdx.x*256 + threadIdx.x;
  if (i < nc)   out_coord[i] = coord[i];
  if (zf && i < nzf) zf[i] = 0.f;
  if (zi && i < nzi) zi[i] = 0;
}

// Wt[c][k] (bf16, zero-padded to Kpad) from W[k][c] (f32, [K,128])
__global__ void egcl_wconv(const float* __restrict__ src, u16* __restrict__ dst,
                           int K, int Kpad)
{
  const int i = blockIdx.x*256 + threadIdx.x;
  if (i >= 128*Kpad) return;
  const int c = i / Kpad, k = i - c*Kpad;
  const float v = (k < K) ? src[(size_t)k*128 + c] : 0.f;
  dst[i] = f2bf(v);
}

__global__ void k_hist(const int* __restrict__ ei, int* __restrict__ hist, int E){
  const int i = blockIdx.x*256 + threadIdx.x;
  if (i < E) atomicAdd(&hist[ei[E + i]], 1);
}
__global__ void k_scan1(const int* __restrict__ hist, int* __restrict__ partial, int N){
  __shared__ int s[256];
  const int t = threadIdx.x, i = blockIdx.x*256 + t;
  s[t] = (i < N) ? hist[i] : 0;
  __syncthreads();
  for (int o=128; o>0; o>>=1){ if (t < o) s[t] += s[t+o]; __syncthreads(); }
  if (t == 0) partial[blockIdx.x] = s[0];
}
__global__ void k_scan2(int* __restrict__ partial, int G){
  if (blockIdx.x == 0 && threadIdx.x == 0){
    int run = 0;
    for (int i=0;i<G;++i){ const int v = partial[i]; partial[i] = run; run += v; }
  }
}
__global__ void k_scan3(const int* __restrict__ hist, const int* __restrict__ partial,
                        int* __restrict__ offs, int* __restrict__ cursor, int N){
  __shared__ int s[256];
  const int t = threadIdx.x, i = blockIdx.x*256 + t;
  const int v = (i < N) ? hist[i] : 0;
  s[t] = v;
  __syncthreads();
  for (int o=1; o<256; o<<=1){
    int x = (t >= o) ? s[t-o] : 0;
    __syncthreads();
    s[t] += x;
    __syncthreads();
  }
  const int ex = s[t] - v + partial[blockIdx.x];
  if (i < N){ offs[i] = ex; cursor[i] = ex; }
}
__global__ void k_scatter(const int* __restrict__ ei, int* __restrict__ cursor,
                          int* __restrict__ elist, int E){
  const int i = blockIdx.x*256 + threadIdx.x;
  if (i < E){
    const int c = ei[E + i];
    const int p = atomicAdd(&cursor[c], 1);
    elist[p] = i;
  }
}

extern "C" void kernel_launch(void* const* d_in, const int* in_sizes, int n_in,
                              void* d_out, int out_size, void* d_ws, size_t ws_size,
                              hipStream_t stream)
{
  const float* h       = (const float*)d_in[0];
  const float* coord   = (const float*)d_in[1];
  const int*   ei      = (const int*)d_in[2];
  const float* ea      = (const float*)d_in[3];
  const float* mes_w1  = (const float*)d_in[4];
  const float* mes_b1  = (const float*)d_in[5];
  const float* mes_w2  = (const float*)d_in[6];
  const float* mes_b2  = (const float*)d_in[7];
  const float* edge_w1 = (const float*)d_in[8];
  const float* edge_b1 = (const float*)d_in[9];
  const float* edge_w2 = (const float*)d_in[10];
  const float* edge_b2 = (const float*)d_in[11];
  const float* node_w1 = (const float*)d_in[12];
  const float* node_b1 = (const float*)d_in[13];
  const float* node_w2 = (const float*)d_in[14];
  const float* node_b2 = (const float*)d_in[15];
  const float* coord_w1= (const float*)d_in[16];
  const float* coord_b1= (const float*)d_in[17];
  const float* coord_w2= (const float*)d_in[18];

  const int N = in_sizes[0] / Hdim;
  const int E = in_sizes[2] / 2;
  const int G1 = (N + 255) / 256;

  char* ws = (char*)d_ws;
  u16* w_mes1t    = (u16*)ws;
  u16* w_mes2t    = w_mes1t  + 128*288;
  u16* w_coord1t  = w_mes2t  + 128*128;
  u16* w_edge1t   = w_coord1t+ 128*128;
  u16* w_edge2t   = w_edge1t + 128*160;
  u16* w_node1t   = w_edge2t + 128*128;
  u16* w_node2t   = w_node1t + 128*256;
  const size_t woff = (((size_t)(288+128+128+160+128+256+128)*128*2) + 255) & ~(size_t)255;

  auto align256 = [](size_t x){ return (x + 255) & ~(size_t)255; };
  const size_t o_feat  = woff;
  const size_t o_hist  = o_feat + align256((size_t)E*Hdim*2);
  const size_t o_offs  = o_hist + align256((size_t)N*4);
  const size_t o_cur   = o_offs + align256((size_t)N*4);
  const size_t o_part  = o_cur  + align256((size_t)N*4);
  const size_t o_elist = o_part + align256((size_t)G1*4);
  const size_t need    = o_elist + (size_t)E*4;
  const bool gather = (ws_size >= need);

  float* out_h     = (float*)d_out;
  float* out_coord = out_h + (size_t)N*Hdim;
  float* out_edge  = out_coord + (size_t)N*3;

  egcl_wconv<<<(128*288 + 255)/256, 256, 0, stream>>>(mes_w1,   w_mes1t,   2*Hdim+1+DEdim, 288);
  egcl_wconv<<<(128*128 + 255)/256, 256, 0, stream>>>(mes_w2,   w_mes2t,   128, 128);
  egcl_wconv<<<(128*128 + 255)/256, 256, 0, stream>>>(coord_w1, w_coord1t, 128, 128);
  egcl_wconv<<<(128*160 + 255)/256, 256, 0, stream>>>(edge_w1,  w_edge1t,  Hdim+1+DEdim, 160);
  egcl_wconv<<<(128*128 + 255)/256, 256, 0, stream>>>(edge_w2,  w_edge2t,  128, 128);
  egcl_wconv<<<(128*256 + 255)/256, 256, 0, stream>>>(node_w1,  w_node1t,  256, 256);
  egcl_wconv<<<(128*128 + 255)/256, 256, 0, stream>>>(node_w2,  w_node2t,  128, 128);

  if (gather){
    u16* feat   = (u16*)(ws + o_feat);
    int* hist   = (int*)(ws + o_hist);
    int* offs   = (int*)(ws + o_offs);
    int* cursor = (int*)(ws + o_cur);
    int* partial= (int*)(ws + o_part);
    int* elist  = (int*)(ws + o_elist);

    egcl_init<<<(N*3 > N ? (N*3+255)/256 : (N+255)/256), 256, 0, stream>>>(
        coord, out_coord, N*3, nullptr, 0, hist, N);
    k_hist<<<(E + 255)/256, 256, 0, stream>>>(ei, hist, E);
    k_scan1<<<G1, 256, 0, stream>>>(hist, partial, N);
    k_scan2<<<1, 64, 0, stream>>>(partial, G1);
    k_scan3<<<G1, 256, 0, stream>>>(hist, partial, offs, cursor, N);
    k_scatter<<<(E + 255)/256, 256, 0, stream>>>(ei, cursor, elist, E);

    egcl_edge<true><<<(E + 63)/64, 256, 0, stream>>>(h, coord, ei, ea,
        mes_b1, mes_b2, edge_b1, edge_b2, coord_b1, coord_w2,
        w_mes1t, w_mes2t, w_coord1t, w_edge1t, w_edge2t,
        nullptr, feat, out_coord, out_edge, E, N);

    egcl_node<true><<<(N + 63)/64, 256, 0, stream>>>(h, nullptr, offs, hist, elist, feat,
        node_b1, node_b2, w_node1t, w_node2t, out_h, N);
  } else {
    float* agg = (float*)(ws + woff);
    egcl_init<<<(N*Hdim + 255)/256, 256, 0, stream>>>(
        coord, out_coord, N*3, agg, N*Hdim, nullptr, 0);

    egcl_edge<false><<<(E + 63)/64, 256, 0, stream>>>(h, coord, ei, ea,
        mes_b1, mes_b2, edge_b1, edge_b2, coord_b1, coord_w2,
        w_mes1t, w_mes2t, w_coord1t, w_edge1t, w_edge2t,
        agg, nullptr, out_coord, out_edge, E, N);

    egcl_node<false><<<(N + 63)/64, 256, 0, stream>>>(h, agg, nullptr, nullptr, nullptr, nullptr,
        node_b1, node_b2, w_node1t, w_node2t, out_h, N);
  }
}